// Round 1
// baseline (518.045 us; speedup 1.0000x reference)
//
#include <hip/hip_runtime.h>
#include <hip/hip_bf16.h>

// QLoRA forward: out = x @ dequant(q_w, scales)^T + 2.0 * (x @ A^T) @ B^T
// M=8192, N=4096, K=4096, rank=16, group=64.
// Strategy: cast to bf16, MFMA GEMM (m97-style 128x128 tile, double-buffered
// global_load_lds staging), LoRA folded in as one extra K-tile (K padded 16->32).

typedef unsigned short u16;
typedef __attribute__((ext_vector_type(8))) short bf16x8;
typedef __attribute__((ext_vector_type(4))) float f32x4;

#define M_DIM 8192
#define N_DIM 4096
#define K_DIM 4096
#define BM 128
#define BN 128
#define BK 32
#define KT_MAIN (K_DIM / BK)   // 128 tiles from x/W
#define NT (KT_MAIN + 1)       // +1 lora tile

// round-to-nearest-even f32 -> bf16
__device__ static inline u16 f2bf(float f) {
    union { float f; unsigned u; } v; v.f = f;
    unsigned r = v.u + 0x7fffu + ((v.u >> 16) & 1u);
    return (u16)(r >> 16);
}

__device__ static inline void gload16(const void* g, void* s) {
    __builtin_amdgcn_global_load_lds(
        (const __attribute__((address_space(1))) void*)g,
        (__attribute__((address_space(3))) void*)s, 16, 0, 0);
}

// ---------------- W dequant: Wb[o][k] = bf16(q[o][k] * scales[o][k/64]) -----
__global__ __launch_bounds__(256) void wprep_kernel(
        const int* __restrict__ q, const float* __restrict__ scales,
        u16* __restrict__ Wb) {
    int idx = blockIdx.x * 256 + threadIdx.x;   // 2,097,152 threads, 8 elems each
    int o  = idx >> 9;            // 512 chunks of 8 per row
    int kc = (idx & 511) << 3;    // k base (8 consecutive, same group)
    float s = scales[(o << 6) + (kc >> 6)];
    const int4* qp = (const int4*)(q + (size_t)o * K_DIM + kc);
    int4 q0 = qp[0], q1 = qp[1];
    ushort4 r0, r1;
    r0.x = f2bf((float)q0.x * s); r0.y = f2bf((float)q0.y * s);
    r0.z = f2bf((float)q0.z * s); r0.w = f2bf((float)q0.w * s);
    r1.x = f2bf((float)q1.x * s); r1.y = f2bf((float)q1.y * s);
    r1.z = f2bf((float)q1.z * s); r1.w = f2bf((float)q1.w * s);
    *(ushort4*)&Wb[(size_t)o * K_DIM + kc]     = r0;
    *(ushort4*)&Wb[(size_t)o * K_DIM + kc + 4] = r1;
}

// ---------------- B2 pack: [4096][32] bf16, cols 16..31 = 0 ----------------
__global__ __launch_bounds__(256) void bprep_kernel(
        const float* __restrict__ lora_B, u16* __restrict__ B2) {
    int idx = blockIdx.x * 256 + threadIdx.x;   // 4096*32
    int o = idx >> 5, r = idx & 31;
    B2[idx] = (r < 16) ? f2bf(lora_B[o * 16 + r]) : (u16)0;
}

// ---------------- x prep (fused): xb = bf16(x); t2 = bf16(2 * x @ A^T) -----
// block = 256 thr = 4 waves; each wave owns 8 m-rows; lane covers k strided.
__global__ __launch_bounds__(256) void xprep_kernel(
        const float* __restrict__ x, const float* __restrict__ lora_A,
        u16* __restrict__ xb, u16* __restrict__ t2) {
    const int tid = threadIdx.x, w = tid >> 6, l = tid & 63;
    const int rb = blockIdx.x * 32 + w * 8;   // wave's first row
    float acc[8][16];
#pragma unroll
    for (int j = 0; j < 8; ++j)
#pragma unroll
        for (int r = 0; r < 16; ++r) acc[j][r] = 0.f;

    for (int i = 0; i < 16; ++i) {
        int k0 = i * 256 + l * 4;             // lane's 4 consecutive k
        float4 xv[8];
#pragma unroll
        for (int j = 0; j < 8; ++j)
            xv[j] = *(const float4*)&x[(size_t)(rb + j) * K_DIM + k0];
#pragma unroll
        for (int j = 0; j < 8; ++j) {
            ushort4 o4;
            o4.x = f2bf(xv[j].x); o4.y = f2bf(xv[j].y);
            o4.z = f2bf(xv[j].z); o4.w = f2bf(xv[j].w);
            *(ushort4*)&xb[(size_t)(rb + j) * K_DIM + k0] = o4;
        }
#pragma unroll
        for (int r = 0; r < 16; ++r) {
            float4 av = *(const float4*)&lora_A[(size_t)r * K_DIM + k0];
#pragma unroll
            for (int j = 0; j < 8; ++j)
                acc[j][r] += xv[j].x * av.x + xv[j].y * av.y
                           + xv[j].z * av.z + xv[j].w * av.w;
        }
    }
    // 64-lane butterfly reduce each of the 128 partials
#pragma unroll
    for (int j = 0; j < 8; ++j)
#pragma unroll
        for (int r = 0; r < 16; ++r) {
            float v = acc[j][r];
            v += __shfl_xor(v, 32); v += __shfl_xor(v, 16);
            v += __shfl_xor(v, 8);  v += __shfl_xor(v, 4);
            v += __shfl_xor(v, 2);  v += __shfl_xor(v, 1);
            acc[j][r] = v;
        }
    // every lane now holds all reduced values; lane l writes (j=l>>4, r=l&15)
    float v0 = 0.f, v1 = 0.f;
#pragma unroll
    for (int j = 0; j < 4; ++j)
#pragma unroll
        for (int r = 0; r < 16; ++r)
            if (l == j * 16 + r) { v0 = acc[j][r]; v1 = acc[j + 4][r]; }
    int row0 = rb + (l >> 4), col = l & 15;
    t2[(size_t)row0 * 32 + col]            = f2bf(2.0f * v0);
    t2[(size_t)(row0 + 4) * 32 + col]      = f2bf(2.0f * v1);
    t2[(size_t)row0 * 32 + 16 + col]       = 0;   // zero pad cols 16..31
    t2[(size_t)(row0 + 4) * 32 + 16 + col] = 0;
}

// ---------------- main GEMM: 128x128 tile, BK=32, 4 waves, dbuf LDS --------
__global__ __launch_bounds__(256) void qlora_gemm(
        const u16* __restrict__ xb, const u16* __restrict__ Wb,
        const u16* __restrict__ t2, const u16* __restrict__ B2,
        float* __restrict__ out) {
    __shared__ u16 ldsA[2][BM * BK];   // 8 KB per buf
    __shared__ u16 ldsB[2][BN * BK];
    const int bn = blockIdx.x, bm = blockIdx.y;
    const int tid = threadIdx.x, w = tid >> 6, l = tid & 63;
    const int wr = w >> 1, wc = w & 1;         // 2x2 wave grid, 64x64 each
    const int fr = l & 15, fq = l >> 4;        // fragment row/quad

    f32x4 acc[4][4] = {};

    // stage tile kt into buffer buf (A:128x32 from xb/t2, B:128x32 from Wb/B2)
    auto stage = [&](int kt, int buf) {
        const char* aSrc; const char* bSrc; int strA, strB;
        if (kt < KT_MAIN) {
            aSrc = (const char*)(xb + (size_t)bm * BM * K_DIM + kt * BK);
            bSrc = (const char*)(Wb + (size_t)bn * BN * K_DIM + kt * BK);
            strA = K_DIM * 2; strB = K_DIM * 2;
        } else {    // lora tile: t2/B2 are [rows][32] contiguous
            aSrc = (const char*)(t2 + (size_t)bm * BM * 32);
            bSrc = (const char*)(B2 + (size_t)bn * BN * 32);
            strA = 64; strB = 64;
        }
        char* aDst = (char*)&ldsA[buf][0] + w * 1024;  // wave-uniform LDS base
        char* bDst = (char*)&ldsB[buf][0] + w * 1024;
        int lo = w * 1024 + l * 16;                    // byte offset in tile
        gload16(aSrc + (lo >> 6) * strA + (lo & 63), aDst);
        gload16(bSrc + (lo >> 6) * strB + (lo & 63), bDst);
        lo += 4096;
        gload16(aSrc + (lo >> 6) * strA + (lo & 63), aDst + 4096);
        gload16(bSrc + (lo >> 6) * strB + (lo & 63), bDst + 4096);
    };

    stage(0, 0);
    __syncthreads();   // vmcnt drained by compiler before s_barrier -> tile 0 ready

    for (int kt = 0; kt < NT; ++kt) {
        int buf = kt & 1;
        if (kt + 1 < NT) stage(kt + 1, buf ^ 1);   // prefetch next tile

        bf16x8 af[4], bfr[4];
#pragma unroll
        for (int i = 0; i < 4; ++i)
            af[i] = *(const bf16x8*)&ldsA[buf][(wr * 64 + i * 16 + fr) * BK + fq * 8];
#pragma unroll
        for (int j = 0; j < 4; ++j)
            bfr[j] = *(const bf16x8*)&ldsB[buf][(wc * 64 + j * 16 + fr) * BK + fq * 8];
#pragma unroll
        for (int i = 0; i < 4; ++i)
#pragma unroll
            for (int j = 0; j < 4; ++j)
                acc[i][j] = __builtin_amdgcn_mfma_f32_16x16x32_bf16(
                                af[i], bfr[j], acc[i][j], 0, 0, 0);
        __syncthreads();   // drains this wave's loads + ds_reads; next tile ready
    }

    // epilogue: C/D layout col=lane&15, row=(lane>>4)*4+reg  [m89-verified]
    float* obase = out + (size_t)(bm * BM + wr * 64 + fq * 4) * N_DIM
                       + bn * BN + wc * 64 + fr;
#pragma unroll
    for (int i = 0; i < 4; ++i)
#pragma unroll
        for (int j = 0; j < 4; ++j)
#pragma unroll
            for (int r = 0; r < 4; ++r)
                obase[(size_t)(i * 16 + r) * N_DIM + j * 16] = acc[i][j][r];
}

extern "C" void kernel_launch(void* const* d_in, const int* in_sizes, int n_in,
                              void* d_out, int out_size, void* d_ws, size_t ws_size,
                              hipStream_t stream) {
    const float* x      = (const float*)d_in[0];
    const int*   qw     = (const int*)d_in[1];
    const float* scales = (const float*)d_in[2];
    const float* lora_A = (const float*)d_in[3];
    const float* lora_B = (const float*)d_in[4];
    float* out = (float*)d_out;

    char* ws = (char*)d_ws;
    // ws layout (needs ~101.5 MB):
    u16* xb = (u16*)(ws);                       // 8192*4096*2 = 67,108,864 B
    u16* Wb = (u16*)(ws + 67108864);            // 4096*4096*2 = 33,554,432 B
    u16* t2 = (u16*)(ws + 100663296);           // 8192*32*2   =    524,288 B
    u16* B2 = (u16*)(ws + 101187584);           // 4096*32*2   =    262,144 B

    wprep_kernel<<<8192, 256, 0, stream>>>(qw, scales, Wb);
    bprep_kernel<<<512, 256, 0, stream>>>(lora_B, B2);
    xprep_kernel<<<256, 256, 0, stream>>>(x, lora_A, xb, t2);
    qlora_gemm<<<dim3(N_DIM / BN, M_DIM / BM), 256, 0, stream>>>(xb, Wb, t2, B2, out);
}

// Round 2
// 365.912 us; speedup vs baseline: 1.4158x; 1.4158x over previous
//
#include <hip/hip_runtime.h>
#include <hip/hip_bf16.h>

// QLoRA forward: out = x @ dequant(q_w, scales)^T + 2.0 * (x @ A^T) @ B^T
// M=8192, N=4096, K=4096, rank=16, group=64.
// GEMM: 256x256 tile, BK=32, 8 waves, TRIPLE-buffered LDS with counted
// vmcnt(4) (loads span barriers, never drain to 0), bank-swizzled via
// pre-swizzled global source, XCD-swizzled grid, setprio on MFMA cluster.
// LoRA folded as 129th K-tile (rank 16 zero-padded to K=32).

typedef unsigned short u16;
typedef __attribute__((ext_vector_type(8))) short bf16x8;
typedef __attribute__((ext_vector_type(4))) float f32x4;

#define M_DIM 8192
#define N_DIM 4096
#define K_DIM 4096
#define BM 256
#define BN 256
#define BK 32
#define KT_MAIN 128
#define NT 129

// round-to-nearest-even f32 -> bf16
__device__ static inline u16 f2bf(float f) {
    union { float f; unsigned u; } v; v.f = f;
    unsigned r = v.u + 0x7fffu + ((v.u >> 16) & 1u);
    return (u16)(r >> 16);
}

__device__ static inline void gload16(const void* g, void* s) {
    __builtin_amdgcn_global_load_lds(
        (const __attribute__((address_space(1))) void*)g,
        (__attribute__((address_space(3))) void*)s, 16, 0, 0);
}

// ---------------- W dequant: Wb[o][k] = bf16(q[o][k] * scales[o][k/64]) -----
__global__ __launch_bounds__(256) void wprep_kernel(
        const int* __restrict__ q, const float* __restrict__ scales,
        u16* __restrict__ Wb) {
    int idx = blockIdx.x * 256 + threadIdx.x;
    int o  = idx >> 9;
    int kc = (idx & 511) << 3;
    float s = scales[(o << 6) + (kc >> 6)];
    const int4* qp = (const int4*)(q + (size_t)o * K_DIM + kc);
    int4 q0 = qp[0], q1 = qp[1];
    ushort4 r0, r1;
    r0.x = f2bf((float)q0.x * s); r0.y = f2bf((float)q0.y * s);
    r0.z = f2bf((float)q0.z * s); r0.w = f2bf((float)q0.w * s);
    r1.x = f2bf((float)q1.x * s); r1.y = f2bf((float)q1.y * s);
    r1.z = f2bf((float)q1.z * s); r1.w = f2bf((float)q1.w * s);
    *(ushort4*)&Wb[(size_t)o * K_DIM + kc]     = r0;
    *(ushort4*)&Wb[(size_t)o * K_DIM + kc + 4] = r1;
}

// ---------------- B2 pack: [4096][32] bf16, cols 16..31 = 0 ----------------
__global__ __launch_bounds__(256) void bprep_kernel(
        const float* __restrict__ lora_B, u16* __restrict__ B2) {
    int idx = blockIdx.x * 256 + threadIdx.x;
    int o = idx >> 5, r = idx & 31;
    B2[idx] = (r < 16) ? f2bf(lora_B[o * 16 + r]) : (u16)0;
}

// ---------------- x prep (fused): xb = bf16(x); t2 = bf16(2 * x @ A^T) -----
// 1024 blocks x 256 thr (4 waves); wave owns 2 rows -> 16 waves/CU occupancy.
__global__ __launch_bounds__(256) void xprep_kernel(
        const float* __restrict__ x, const float* __restrict__ lora_A,
        u16* __restrict__ xb, u16* __restrict__ t2) {
    const int tid = threadIdx.x, w = tid >> 6, l = tid & 63;
    const int rb = blockIdx.x * 8 + w * 2;     // wave's 2 rows
    float acc[2][16];
#pragma unroll
    for (int j = 0; j < 2; ++j)
#pragma unroll
        for (int r = 0; r < 16; ++r) acc[j][r] = 0.f;

    for (int i = 0; i < 16; ++i) {
        int k0 = i * 256 + l * 4;
        float4 x0 = *(const float4*)&x[(size_t)rb * K_DIM + k0];
        float4 x1 = *(const float4*)&x[(size_t)(rb + 1) * K_DIM + k0];
        ushort4 o0, o1;
        o0.x = f2bf(x0.x); o0.y = f2bf(x0.y); o0.z = f2bf(x0.z); o0.w = f2bf(x0.w);
        o1.x = f2bf(x1.x); o1.y = f2bf(x1.y); o1.z = f2bf(x1.z); o1.w = f2bf(x1.w);
        *(ushort4*)&xb[(size_t)rb * K_DIM + k0]       = o0;
        *(ushort4*)&xb[(size_t)(rb + 1) * K_DIM + k0] = o1;
#pragma unroll
        for (int r = 0; r < 16; ++r) {
            float4 av = *(const float4*)&lora_A[(size_t)r * K_DIM + k0];
            acc[0][r] += x0.x * av.x + x0.y * av.y + x0.z * av.z + x0.w * av.w;
            acc[1][r] += x1.x * av.x + x1.y * av.y + x1.z * av.z + x1.w * av.w;
        }
    }
#pragma unroll
    for (int j = 0; j < 2; ++j)
#pragma unroll
        for (int r = 0; r < 16; ++r) {
            float v = acc[j][r];
            v += __shfl_xor(v, 32); v += __shfl_xor(v, 16);
            v += __shfl_xor(v, 8);  v += __shfl_xor(v, 4);
            v += __shfl_xor(v, 2);  v += __shfl_xor(v, 1);
            acc[j][r] = v;
        }
    float v = 0.f;
#pragma unroll
    for (int j = 0; j < 2; ++j)
#pragma unroll
        for (int r = 0; r < 16; ++r)
            if (l == j * 16 + r) v = acc[j][r];
    int row = (l >> 4) & 1, col = (l & 15) + ((l >= 32) ? 16 : 0);
    u16 outv = (l < 32) ? f2bf(2.0f * v) : (u16)0;   // cols 16..31 zero pad
    t2[(size_t)(rb + row) * 32 + col] = outv;
}

// ---------------- main GEMM ------------------------------------------------
// LDS per buf: A = 256x32 bf16 (16KB, bytes [0,16384)), B same ([16384,32768)).
// Swizzle: logical 16B-slot s of row r stored at phys slot s ^ ((r>>1)&3).
// gload_lds writes linearly; the SOURCE address is pre-swizzled to match.
__global__ __launch_bounds__(512, 2) void qlora_gemm(
        const u16* __restrict__ xb, const u16* __restrict__ Wb,
        const u16* __restrict__ t2, const u16* __restrict__ B2,
        float* __restrict__ out) {
    __shared__ u16 lds[3][16384];                 // 96 KB
    // XCD-aware bijective swizzle: 512 blocks = 8 XCDs x 64
    int bid = blockIdx.x;
    int swz = (bid & 7) * 64 + (bid >> 3);
    int bn = swz >> 5;                            // 0..15  (N panels; 2 per XCD chunk)
    int bm = swz & 31;                            // 0..31
    const int tid = threadIdx.x, w = tid >> 6, l = tid & 63;
    const int wr = w >> 2, wc = w & 3;            // 2x4 wave grid, 128x64 per wave
    const int fr = l & 15, fq = l >> 4;
    const int sA = fq ^ ((fr >> 1) & 3);          // swizzled slot for frag reads

    // staging precompute: thread covers tile-row rs (q=0) and rs+128 (q=1)
    const int rs   = w * 16 + (l >> 2);
    const int sl16 = ((l & 3) ^ ((l >> 3) & 3)) << 4;   // pre-swizzled src k-offset
    const char* aRow0 = (const char*)xb + (((size_t)(bm * 256 + rs)) << 13) + sl16;
    const char* aRow1 = aRow0 + (size_t)(128u << 13);
    const char* bRow0 = (const char*)Wb + (((size_t)(bn * 256 + rs)) << 13) + sl16;
    const char* bRow1 = bRow0 + (size_t)(128u << 13);
    const char* aL0 = (const char*)t2 + (size_t)(bm * 256 + rs) * 64 + sl16;
    const char* aL1 = aL0 + 128 * 64;
    const char* bL0 = (const char*)B2 + (size_t)(bn * 256 + rs) * 64 + sl16;
    const char* bL1 = bL0 + 128 * 64;
    char* ldsC = (char*)&lds[0][0];
    const int dA = w * 1024;                      // wave-uniform LDS dest (+q*8192)
    const int dB = 16384 + w * 1024;

    // frag-read byte offsets (within a buffer)
    const int aoff = (wr * 128 + fr) * 64 + sA * 16;           // + i*1024
    const int boff = 16384 + (wc * 64 + fr) * 64 + sA * 16;    // + j*1024

    f32x4 acc[8][4] = {};

    auto stage = [&](int kt, int buf) {
        char* base = ldsC + buf * 32768;
        if (kt < KT_MAIN) {
            size_t ko = (size_t)kt * 64;
            gload16(aRow0 + ko, base + dA);
            gload16(aRow1 + ko, base + dA + 8192);
            gload16(bRow0 + ko, base + dB);
            gload16(bRow1 + ko, base + dB + 8192);
        } else {            // lora tile: t2/B2 are [rows][32] (64B rows)
            gload16(aL0, base + dA);
            gload16(aL1, base + dA + 8192);
            gload16(bL0, base + dB);
            gload16(bL1, base + dB + 8192);
        }
    };

    stage(0, 0);
    stage(1, 1);
    asm volatile("s_waitcnt vmcnt(4)" ::: "memory");   // tile 0 landed
    __builtin_amdgcn_s_barrier();
    asm volatile("" ::: "memory");

    for (int t = 0; t < NT; ++t) {
        const int bufC = t % 3;
        if (t + 2 < NT) stage(t + 2, (t + 2) % 3);     // write buf nobody reads
        const char* cb = ldsC + bufC * 32768;
        bf16x8 af[8], bfr[4];
#pragma unroll
        for (int j = 0; j < 4; ++j)
            bfr[j] = *(const bf16x8*)(cb + boff + j * 1024);
#pragma unroll
        for (int i = 0; i < 8; ++i)
            af[i] = *(const bf16x8*)(cb + aoff + i * 1024);
        __builtin_amdgcn_s_setprio(1);
#pragma unroll
        for (int i = 0; i < 8; ++i)
#pragma unroll
            for (int j = 0; j < 4; ++j)
                acc[i][j] = __builtin_amdgcn_mfma_f32_16x16x32_bf16(
                                af[i], bfr[j], acc[i][j], 0, 0, 0);
        __builtin_amdgcn_s_setprio(0);
        if (t + 1 < NT) {
            if (t + 2 < NT)
                asm volatile("s_waitcnt vmcnt(4)" ::: "memory");  // t+1 landed, t+2 in flight
            else
                asm volatile("s_waitcnt vmcnt(0)" ::: "memory");  // tail drain
            __builtin_amdgcn_s_barrier();
            asm volatile("" ::: "memory");
        }
    }

    // epilogue: C/D layout col=lane&15, row=(lane>>4)*4+reg  [validated round 1]
    float* obase = out + (size_t)(bm * 256 + wr * 128 + fq * 4) * N_DIM
                       + bn * 256 + wc * 64 + fr;
#pragma unroll
    for (int i = 0; i < 8; ++i)
#pragma unroll
        for (int j = 0; j < 4; ++j)
#pragma unroll
            for (int r = 0; r < 4; ++r)
                obase[(size_t)(i * 16 + r) * N_DIM + j * 16] = acc[i][j][r];
}

extern "C" void kernel_launch(void* const* d_in, const int* in_sizes, int n_in,
                              void* d_out, int out_size, void* d_ws, size_t ws_size,
                              hipStream_t stream) {
    const float* x      = (const float*)d_in[0];
    const int*   qw     = (const int*)d_in[1];
    const float* scales = (const float*)d_in[2];
    const float* lora_A = (const float*)d_in[3];
    const float* lora_B = (const float*)d_in[4];
    float* out = (float*)d_out;

    char* ws = (char*)d_ws;
    u16* xb = (u16*)(ws);                       // 8192*4096*2 = 67,108,864 B
    u16* Wb = (u16*)(ws + 67108864);            // 4096*4096*2 = 33,554,432 B
    u16* t2 = (u16*)(ws + 100663296);           // 8192*32*2   =    524,288 B
    u16* B2 = (u16*)(ws + 101187584);           // 4096*32*2   =    262,144 B

    wprep_kernel<<<8192, 256, 0, stream>>>(qw, scales, Wb);
    bprep_kernel<<<512, 256, 0, stream>>>(lora_B, B2);
    xprep_kernel<<<1024, 256, 0, stream>>>(x, lora_A, xb, t2);
    qlora_gemm<<<dim3(512), 512, 0, stream>>>(xb, Wb, t2, B2, out);
}